// Round 13
// baseline (96.852 us; speedup 1.0000x reference)
//
#include <hip/hip_runtime.h>

#define NHEADS 16
#define NW 8
#define SEQ 1024
#define BATCH 8
#define EMB 128

typedef _Float16 half2_t __attribute__((ext_vector_type(2)));
typedef _Float16 half4_t __attribute__((ext_vector_type(4)));
typedef _Float16 half8_t __attribute__((ext_vector_type(8)));
typedef float    f32x4   __attribute__((ext_vector_type(4)));

__device__ __forceinline__ half2_t pkrtz(float a, float b) {
    return __builtin_bit_cast(half2_t, __builtin_amdgcn_cvt_pkrtz(a, b));
}

// qattn smem layout in halves:
//   kvh  [1024 keys][8 dims]            @ 0      (16 KB, row-major)
//   kvhT [8 dims][stride 1040]          @ 8192   (16.25 KB, transposed, padded)
//   ones [8]                            @ 16512
//   zero [8]                            @ 16520
#define KVT       8192
#define KVT_STR   1040
#define ONES_OFF  16512
#define ZERO_OFF  16520
#define SMEM_H    16544        // + pad for last-iteration prefetch overrun

// quantum_heads closed form for one (b,s,head) row (fp32 input):
// c[w] = cos(x[w] + theta[w]); z[0] = c1..c7; z[w>=1] = c0..cw
__device__ __forceinline__ void qrow(const float* __restrict__ xp,
                                     const float* __restrict__ th, float* z) {
    float4 a = *reinterpret_cast<const float4*>(xp);
    float4 b = *reinterpret_cast<const float4*>(xp + 4);
    float c0 = __cosf(a.x + th[0]);
    float c1 = __cosf(a.y + th[1]);
    float c2 = __cosf(a.z + th[2]);
    float c3 = __cosf(a.w + th[3]);
    float c4 = __cosf(b.x + th[4]);
    float c5 = __cosf(b.y + th[5]);
    float c6 = __cosf(b.z + th[6]);
    float c7 = __cosf(b.w + th[7]);
    float u = c1 * c2;
    u *= c3; u *= c4; u *= c5; u *= c6; u *= c7;
    z[0] = u;
    z[1] = c0 * c1;
    z[2] = z[1] * c2;
    z[3] = z[2] * c3;
    z[4] = z[3] * c4;
    z[5] = z[4] * c5;
    z[6] = z[5] * c6;
    z[7] = z[6] * c7;
}

// MFMA attention (R11-verified layouts). grid = 128 bh * 16 qsplits = 2048
// blocks (8 blocks/CU -> 32 waves/CU), 256 threads, 1 q-tile of 16 per wave.
// K-loop: 32 iters x 32 keys.
//   S^T = K.Q^T   (2x mfma 16x16x32 f16, d=8 zero-padded in K dim)
//   P   = exp2(S^T)  (QS*log2e folded into Q-frag)
//   O^T = Vx^T.P^T accumulated (Vx has ones col at dim 8 -> row-sum l)
// C->B transform: conflict-free 4-bpermute schedule (R11-verified).
__global__ __launch_bounds__(256, 8) void qattn_mfma(
    const float* __restrict__ x,
    const float* __restrict__ theta,
    __fp16* __restrict__ P)        // [B*S][128] f16, normalized attn@h
{
    __shared__ __align__(16) _Float16 smem[SMEM_H];
    const int t   = threadIdx.x;
    const int bid = blockIdx.x;
    const int qs  = bid & 15;               // query 1/16th (64 q)
    const int bh  = bid >> 4;               // 0..127
    const int b   = bh >> 4, h = bh & 15;

    float th[8];
#pragma unroll
    for (int w = 0; w < 8; ++w) th[w] = theta[w];   // wave-uniform -> s_loads

    // ---- stage all 1024 keys: row-major f16 + transposed copy ----
#pragma unroll
    for (int i = 0; i < 4; ++i) {
        const int kl = t + 256 * i;
        float z[8];
        qrow(x + ((size_t)(b * SEQ + kl) * EMB + h * NW), th, z);
        half8_t hv;
#pragma unroll
        for (int d = 0; d < 8; ++d) hv[d] = (_Float16)z[d];
        *reinterpret_cast<half8_t*>(&smem[kl * 8]) = hv;
#pragma unroll
        for (int d = 0; d < 8; ++d) smem[KVT + d * KVT_STR + kl] = hv[d];
    }
    if (t < 8)              smem[ONES_OFF + t]     = (_Float16)1.0f;
    else if (t < 16)        smem[ZERO_OFF + t - 8] = (_Float16)0.0f;
    __syncthreads();

    const int lane = t & 63;
    const int wv   = t >> 6;
    const int q16  = lane & 15;
    const int qd   = lane >> 4;             // quad 0..3
    const int qbase = qs * 64 + wv * 16;

    // ---- Q fragment (B operand): B[k=dim][n=q], quads!=0 read zeros ----
    const _Float16 QSh = (_Float16)0.51012924f;   // (1/sqrt(8))*log2(e)
    half8_t qfrag;
    {
        const _Float16* qp = (qd == 0)
            ? &smem[(qbase + q16) * 8] : &smem[ZERO_OFF];
        half8_t qv = *reinterpret_cast<const half8_t*>(qp);
#pragma unroll
        for (int j = 0; j < 8; ++j) qv[j] = qv[j] * QSh;
        qfrag = qv;
    }

    // ---- loop-invariant pointers / lane constants ----
    const _Float16* ka = (qd == 0) ? &smem[q16 * 8]        : &smem[ZERO_OFF];
    const _Float16* kb = (qd == 0) ? &smem[(16 + q16) * 8] : &smem[ZERO_OFF];
    const int kstep = (qd == 0) ? 256 : 0;          // 32 keys * 8 halves
    const _Float16* vp; int vstep;
    if (q16 < 8)       { vp = &smem[KVT + q16 * KVT_STR + qd * 8]; vstep = 32; }
    else if (q16 == 8) { vp = &smem[ONES_OFF]; vstep = 0; }
    else               { vp = &smem[ZERO_OFF]; vstep = 0; }

    const bool oddq = (qd & 1);                         // source-side publication
    const bool hiC  = (qd >= 2);                        // dest-side swap
    const int  iA   = (q16 + (qd & 1) * 32 + (qd >> 1) * 16) * 4;
    const int  iB   = iA ^ 64;
    const int  lidx = (32 + q16) * 4;                   // lane holding dim-8 row (l)

    f32x4 oacc = {0.f, 0.f, 0.f, 0.f};
    const f32x4 zc = {0.f, 0.f, 0.f, 0.f};

    half8_t kA = *reinterpret_cast<const half8_t*>(ka);
    half8_t kB = *reinterpret_cast<const half8_t*>(kb);
    half8_t vA = *reinterpret_cast<const half8_t*>(vp);

#pragma unroll 2
    for (int kt = 0; kt < 32; ++kt) {
        ka += kstep; kb += kstep; vp += vstep;
        half8_t nkA = *reinterpret_cast<const half8_t*>(ka);   // prefetch (pad-safe)
        half8_t nkB = *reinterpret_cast<const half8_t*>(kb);
        half8_t nvA = *reinterpret_cast<const half8_t*>(vp);

        // S^T tiles: C[row=key=qd*4+reg][col=q=lane&15]
        f32x4 c0 = __builtin_amdgcn_mfma_f32_16x16x32_f16(kA, qfrag, zc, 0, 0, 0);
        f32x4 c1 = __builtin_amdgcn_mfma_f32_16x16x32_f16(kB, qfrag, zc, 0, 0, 0);
        // p0/p1 = local keys 4qd+{0,1}/{2,3}; p2/p3 = keys 16+4qd+{0,1}/{2,3}
        half2_t p0 = pkrtz(__builtin_amdgcn_exp2f(c0[0]), __builtin_amdgcn_exp2f(c0[1]));
        half2_t p1 = pkrtz(__builtin_amdgcn_exp2f(c0[2]), __builtin_amdgcn_exp2f(c0[3]));
        half2_t p2 = pkrtz(__builtin_amdgcn_exp2f(c1[0]), __builtin_amdgcn_exp2f(c1[1]));
        half2_t p3 = pkrtz(__builtin_amdgcn_exp2f(c1[2]), __builtin_amdgcn_exp2f(c1[3]));
        union { half2_t h; int i; } u0, u1, u2, u3;
        u0.h = p0; u1.h = p1; u2.h = p2; u3.h = p3;
        // publication: quads {0,2} -> (p0,p1,p2,p3); quads {1,3} -> (p2,p3,p0,p1)
        const int a0 = oddq ? u2.i : u0.i;
        const int a1 = oddq ? u3.i : u1.i;
        const int a2 = oddq ? u0.i : u2.i;
        const int a3 = oddq ? u1.i : u3.i;
        const int r0 = __builtin_amdgcn_ds_bpermute(iA, a0);
        const int r1 = __builtin_amdgcn_ds_bpermute(iA, a1);
        const int r2 = __builtin_amdgcn_ds_bpermute(iB, a2);
        const int r3 = __builtin_amdgcn_ds_bpermute(iB, a3);
        // assemble B-operand P^T frag: element j = P[key=qd*8+j][q=lane&15]
        union { int i[4]; half8_t h; } bf;
        bf.i[0] = hiC ? r2 : r0;
        bf.i[1] = hiC ? r3 : r1;
        bf.i[2] = hiC ? r0 : r2;
        bf.i[3] = hiC ? r1 : r3;
        // O^T += Vx^T . P^T  (ones col -> row-sum l in dim 8)
        oacc = __builtin_amdgcn_mfma_f32_16x16x32_f16(vA, bf.h, oacc, 0, 0, 0);

        kA = nkA; kB = nkB; vA = nvA;
    }

    // ---- epilogue: normalize by l (row 8 = quad2 reg0), write P f16 ----
    {
        f32x4 c = oacc;
        const float lsum = __int_as_float(
            __builtin_amdgcn_ds_bpermute(lidx, __float_as_int(c[0])));
        const float inv = 1.0f / lsum;
        if (qd < 2) {                       // quads 0,1 hold dims 0-7
            half2_t u0 = pkrtz(c[0] * inv, c[1] * inv);
            half2_t u1 = pkrtz(c[2] * inv, c[3] * inv);
            half4_t o4; o4[0] = u0[0]; o4[1] = u0[1]; o4[2] = u1[0]; o4[3] = u1[1];
            const int row = b * SEQ + qbase + q16;
            *reinterpret_cast<half4_t*>(
                reinterpret_cast<_Float16*>(P) + (size_t)row * EMB + h * NW + qd * 4) = o4;
        }
    }
}

// MFMA projection with fused W f32->f16 conversion:
// out[row][e] = sum_f P[row][f]*W[e][f] + bias[e].
// No LDS, no barriers; A frags from global P (L2-hot), B frags converted
// in-register from f32 W (L2-hot). grid = 512 x 256.
// Frag layouts hardware-verified in R11.
__global__ __launch_bounds__(256) void proj_mfma(
    const __fp16* __restrict__ Pv,
    const float* __restrict__ W,
    const float* __restrict__ bias,
    float* __restrict__ out)
{
    const _Float16* P = reinterpret_cast<const _Float16*>(Pv);
    const int t    = threadIdx.x;
    const int lane = t & 63;
    const int wv   = t >> 6;
    const int n16  = lane & 15;
    const int qd   = lane >> 4;
    const int row0 = blockIdx.x * 16;
    const int col0 = wv * 32;

    // A fragments: P rows, k = kb*32 + qd*8 + j (contiguous half8)
    half8_t a[4];
#pragma unroll
    for (int kb = 0; kb < 4; ++kb)
        a[kb] = *reinterpret_cast<const half8_t*>(
            P + (size_t)(row0 + n16) * EMB + kb * 32 + qd * 8);

    const f32x4 zc = {0.f, 0.f, 0.f, 0.f};
#pragma unroll
    for (int et = 0; et < 2; ++et) {
        const int e = col0 + et * 16 + n16;
        f32x4 acc = zc;
#pragma unroll
        for (int kb = 0; kb < 4; ++kb) {
            const float* wp = W + (size_t)e * EMB + kb * 32 + qd * 8;
            float4 w0 = *reinterpret_cast<const float4*>(wp);
            float4 w1 = *reinterpret_cast<const float4*>(wp + 4);
            half2_t h0 = pkrtz(w0.x, w0.y);
            half2_t h1 = pkrtz(w0.z, w0.w);
            half2_t h2 = pkrtz(w1.x, w1.y);
            half2_t h3 = pkrtz(w1.z, w1.w);
            half8_t bfr;
            bfr[0] = h0[0]; bfr[1] = h0[1]; bfr[2] = h1[0]; bfr[3] = h1[1];
            bfr[4] = h2[0]; bfr[5] = h2[1]; bfr[6] = h3[0]; bfr[7] = h3[1];
            acc = __builtin_amdgcn_mfma_f32_16x16x32_f16(a[kb], bfr, acc, 0, 0, 0);
        }
        const float bv = bias[e];
#pragma unroll
        for (int r = 0; r < 4; ++r)
            out[(size_t)(row0 + qd * 4 + r) * EMB + e] = acc[r] + bv;
    }
}

extern "C" void kernel_launch(void* const* d_in, const int* in_sizes, int n_in,
                              void* d_out, int out_size, void* d_ws, size_t ws_size,
                              hipStream_t stream)
{
    const float* x     = (const float*)d_in[0];
    const float* theta = (const float*)d_in[1];
    const float* W     = (const float*)d_in[2];
    const float* bias  = (const float*)d_in[3];
    float* out = (float*)d_out;

    __fp16* Pw = (__fp16*)d_ws;                              // 2 MB

    qattn_mfma<<<128 * 16, 256, 0, stream>>>(x, theta, Pw);
    proj_mfma<<<BATCH * SEQ / 16, 256, 0, stream>>>(Pw, W, bias, out);
}

// Round 14
// 89.373 us; speedup vs baseline: 1.0837x; 1.0837x over previous
//
#include <hip/hip_runtime.h>

#define NHEADS 16
#define NW 8
#define SEQ 1024
#define BATCH 8
#define EMB 128

typedef _Float16 half2_t __attribute__((ext_vector_type(2)));
typedef _Float16 half4_t __attribute__((ext_vector_type(4)));
typedef _Float16 half8_t __attribute__((ext_vector_type(8)));
typedef float    f32x4   __attribute__((ext_vector_type(4)));
typedef int      i32x2   __attribute__((ext_vector_type(2)));

__device__ __forceinline__ half2_t pkrtz(float a, float b) {
    return __builtin_bit_cast(half2_t, __builtin_amdgcn_cvt_pkrtz(a, b));
}

#if __has_builtin(__builtin_amdgcn_permlane16_swap)
#define HAVE_PLSWAP 1
#else
#define HAVE_PLSWAP 0
#endif

// qattn smem layout in halves:
//   kvh  [1024 keys][8 dims]      @ 0        (16 KB, row-major)
//   kvhT [8 dims][stride 1042]    @ 8192     (transposed; dword stride 521 == 9 mod 32)
//   ones [8] / zero [8]           @ 16528 / 16536
#define KVT       8192
#define KVT_STR   1042
#define ONES_OFF  (KVT + 8 * KVT_STR)      // 16528
#define ZERO_OFF  (ONES_OFF + 8)           // 16536
#define SMEM_H    (ZERO_OFF + 72)          // slack for last-iter prefetch overrun

// quantum_heads closed form for one (b,s,head) row (fp32 input):
// c[w] = cos(x[w] + theta[w]); z[0] = c1..c7; z[w>=1] = c0..cw
__device__ __forceinline__ void qrow(const float* __restrict__ xp,
                                     const float* __restrict__ th, float* z) {
    float4 a = *reinterpret_cast<const float4*>(xp);
    float4 b = *reinterpret_cast<const float4*>(xp + 4);
    float c0 = __cosf(a.x + th[0]);
    float c1 = __cosf(a.y + th[1]);
    float c2 = __cosf(a.z + th[2]);
    float c3 = __cosf(a.w + th[3]);
    float c4 = __cosf(b.x + th[4]);
    float c5 = __cosf(b.y + th[5]);
    float c6 = __cosf(b.z + th[6]);
    float c7 = __cosf(b.w + th[7]);
    float u = c1 * c2;
    u *= c3; u *= c4; u *= c5; u *= c6; u *= c7;
    z[0] = u;
    z[1] = c0 * c1;
    z[2] = z[1] * c2;
    z[3] = z[2] * c3;
    z[4] = z[3] * c4;
    z[5] = z[4] * c5;
    z[6] = z[5] * c6;
    z[7] = z[6] * c7;
}

// MFMA attention (R11-verified layouts; transform moved to VALU permlane swaps).
// grid = 128 bh * 8 qsplits = 1024 blocks, 256 threads, 2 q-tiles/wave.
__global__ __launch_bounds__(256, 4) void qattn_mfma(
    const float* __restrict__ x,
    const float* __restrict__ theta,
    __fp16* __restrict__ P)        // [B*S][128] f16, normalized attn@h
{
    __shared__ __align__(16) _Float16 smem[SMEM_H];
    const int t   = threadIdx.x;
    const int bid = blockIdx.x;
    const int qs  = bid & 7;                // query octant (128 q)
    const int bh  = bid >> 3;               // 0..127
    const int b   = bh >> 4, h = bh & 15;

    float th[8];
#pragma unroll
    for (int w = 0; w < 8; ++w) th[w] = theta[w];   // wave-uniform -> s_loads

    // ---- stage all 1024 keys: row-major f16 + transposed copy ----
#pragma unroll
    for (int i = 0; i < 4; ++i) {
        const int kl = t + 256 * i;
        float z[8];
        qrow(x + ((size_t)(b * SEQ + kl) * EMB + h * NW), th, z);
        half8_t hv;
#pragma unroll
        for (int d = 0; d < 8; ++d) hv[d] = (_Float16)z[d];
        *reinterpret_cast<half8_t*>(&smem[kl * 8]) = hv;
#pragma unroll
        for (int d = 0; d < 8; ++d) smem[KVT + d * KVT_STR + kl] = hv[d];
    }
    if (t < 8)              smem[ONES_OFF + t]     = (_Float16)1.0f;
    else if (t < 16)        smem[ZERO_OFF + t - 8] = (_Float16)0.0f;
    __syncthreads();

    const int lane = t & 63;
    const int wv   = t >> 6;
    const int q16  = lane & 15;
    const int qd   = lane >> 4;             // quad 0..3
    const int qbase = qs * 128 + wv * 32;

    // ---- Q fragments (B operand): B[k=dim][n=q], quads!=0 read zeros ----
    const _Float16 QSh = (_Float16)0.51012924f;   // (1/sqrt(8))*log2(e)
    half8_t qfrag[2];
#pragma unroll
    for (int qi = 0; qi < 2; ++qi) {
        const _Float16* qp = (qd == 0)
            ? &smem[(qbase + qi * 16 + q16) * 8] : &smem[ZERO_OFF];
        half8_t qv = *reinterpret_cast<const half8_t*>(qp);
#pragma unroll
        for (int j = 0; j < 8; ++j) qv[j] = qv[j] * QSh;
        qfrag[qi] = qv;
    }

    // ---- loop-invariant pointers / lane constants ----
    const _Float16* ka = (qd == 0) ? &smem[q16 * 8]        : &smem[ZERO_OFF];
    const _Float16* kb = (qd == 0) ? &smem[(16 + q16) * 8] : &smem[ZERO_OFF];
    const int kstep = (qd == 0) ? 256 : 0;          // 32 keys * 8 halves

    // V-operand (A-op of PV MFMA) dword loads; key order kappa matches the
    // permlane-swap output (or consecutive for the bpermute fallback).
    const unsigned int* vb; int vo0, vo1, vo2, vo3; int vstep;
    if (q16 < 8) {
        vb = reinterpret_cast<const unsigned int*>(&smem[KVT + q16 * KVT_STR]);
#if HAVE_PLSWAP
        const int bo = (qd & 1) + (qd >> 1) * 4;
        vo0 = bo; vo1 = bo + 2; vo2 = bo + 8; vo3 = bo + 10;
#else
        vo0 = qd * 4; vo1 = vo0 + 1; vo2 = vo0 + 2; vo3 = vo0 + 3;
#endif
        vstep = 16;                                  // 32 keys = 16 dwords
    } else if (q16 == 8) {
        vb = reinterpret_cast<const unsigned int*>(&smem[ONES_OFF]);
        vo0 = vo1 = vo2 = vo3 = 0; vstep = 0;
    } else {
        vb = reinterpret_cast<const unsigned int*>(&smem[ZERO_OFF]);
        vo0 = vo1 = vo2 = vo3 = 0; vstep = 0;
    }

#if !HAVE_PLSWAP
    const bool oddq = (qd & 1);
    const bool hiC  = (qd >= 2);
    const int  iA   = (q16 + (qd & 1) * 32 + (qd >> 1) * 16) * 4;
    const int  iB   = iA ^ 64;
#endif
    const int  lidx = (32 + q16) * 4;               // lane holding dim-8 row (l)

    f32x4 oacc[2] = {{0.f, 0.f, 0.f, 0.f}, {0.f, 0.f, 0.f, 0.f}};
    const f32x4 zc = {0.f, 0.f, 0.f, 0.f};

    half8_t kA = *reinterpret_cast<const half8_t*>(ka);
    half8_t kB = *reinterpret_cast<const half8_t*>(kb);
    unsigned int v0 = vb[vo0], v1 = vb[vo1], v2 = vb[vo2], v3 = vb[vo3];

    for (int kt = 0; kt < 32; ++kt) {
        ka += kstep; kb += kstep; vb += vstep;
        half8_t nkA = *reinterpret_cast<const half8_t*>(ka);   // prefetch (pad-safe)
        half8_t nkB = *reinterpret_cast<const half8_t*>(kb);
        unsigned int nv0 = vb[vo0], nv1 = vb[vo1], nv2 = vb[vo2], nv3 = vb[vo3];

        union { unsigned int i[4]; half8_t h; } vf;
        vf.i[0] = v0; vf.i[1] = v1; vf.i[2] = v2; vf.i[3] = v3;

#pragma unroll
        for (int qi = 0; qi < 2; ++qi) {
            // S^T tiles: C[row=key=qd*4+reg][col=q=lane&15]
            f32x4 c0 = __builtin_amdgcn_mfma_f32_16x16x32_f16(kA, qfrag[qi], zc, 0, 0, 0);
            f32x4 c1 = __builtin_amdgcn_mfma_f32_16x16x32_f16(kB, qfrag[qi], zc, 0, 0, 0);
            // p0/p1 = local keys 4qd+{0,1}/{2,3}; p2/p3 = keys 16+4qd+{0,1}/{2,3}
            half2_t p0 = pkrtz(__builtin_amdgcn_exp2f(c0[0]), __builtin_amdgcn_exp2f(c0[1]));
            half2_t p1 = pkrtz(__builtin_amdgcn_exp2f(c0[2]), __builtin_amdgcn_exp2f(c0[3]));
            half2_t p2 = pkrtz(__builtin_amdgcn_exp2f(c1[0]), __builtin_amdgcn_exp2f(c1[1]));
            half2_t p3 = pkrtz(__builtin_amdgcn_exp2f(c1[2]), __builtin_amdgcn_exp2f(c1[3]));
            union { half2_t h; int i; } u0, u1, u2, u3;
            u0.h = p0; u1.h = p1; u2.h = p2; u3.h = p3;
            union { int i[4]; half8_t h; } bf;
#if HAVE_PLSWAP
            // VALU transform: rows exchange; resulting key order is kappa(qd)
            // (V offsets above match it pairwise, so the contraction is exact).
            i32x2 s01 = __builtin_amdgcn_permlane16_swap(u0.i, u1.i, false, false);
            i32x2 s23 = __builtin_amdgcn_permlane16_swap(u2.i, u3.i, false, false);
            bf.i[0] = s01[0]; bf.i[1] = s01[1];
            bf.i[2] = s23[0]; bf.i[3] = s23[1];
#else
            // R11 bpermute path (DS pipe), consecutive key order
            const int a0 = oddq ? u2.i : u0.i;
            const int a1 = oddq ? u3.i : u1.i;
            const int a2 = oddq ? u0.i : u2.i;
            const int a3 = oddq ? u1.i : u3.i;
            const int r0 = __builtin_amdgcn_ds_bpermute(iA, a0);
            const int r1 = __builtin_amdgcn_ds_bpermute(iA, a1);
            const int r2 = __builtin_amdgcn_ds_bpermute(iB, a2);
            const int r3 = __builtin_amdgcn_ds_bpermute(iB, a3);
            bf.i[0] = hiC ? r2 : r0;
            bf.i[1] = hiC ? r3 : r1;
            bf.i[2] = hiC ? r0 : r2;
            bf.i[3] = hiC ? r1 : r3;
#endif
            // O^T += Vx^T . P^T  (ones col -> row-sum l in dim 8)
            oacc[qi] = __builtin_amdgcn_mfma_f32_16x16x32_f16(vf.h, bf.h, oacc[qi], 0, 0, 0);
        }
        kA = nkA; kB = nkB;
        v0 = nv0; v1 = nv1; v2 = nv2; v3 = nv3;
    }

    // ---- epilogue: normalize by l (row 8 = quad2 reg0), write P f16 ----
#pragma unroll
    for (int qi = 0; qi < 2; ++qi) {
        f32x4 c = oacc[qi];
        const float lsum = __int_as_float(
            __builtin_amdgcn_ds_bpermute(lidx, __float_as_int(c[0])));
        const float inv = 1.0f / lsum;
        if (qd < 2) {                       // quads 0,1 hold dims 0-7
            half2_t u0 = pkrtz(c[0] * inv, c[1] * inv);
            half2_t u1 = pkrtz(c[2] * inv, c[3] * inv);
            half4_t o4; o4[0] = u0[0]; o4[1] = u0[1]; o4[2] = u1[0]; o4[3] = u1[1];
            const int row = b * SEQ + qbase + qi * 16 + q16;
            *reinterpret_cast<half4_t*>(
                reinterpret_cast<_Float16*>(P) + (size_t)row * EMB + h * NW + qd * 4) = o4;
        }
    }
}

// MFMA projection with fused W f32->f16 conversion (R12-verified):
// out[row][e] = sum_f P[row][f]*W[e][f] + bias[e]. No LDS, no barriers.
__global__ __launch_bounds__(256) void proj_mfma(
    const __fp16* __restrict__ Pv,
    const float* __restrict__ W,
    const float* __restrict__ bias,
    float* __restrict__ out)
{
    const _Float16* P = reinterpret_cast<const _Float16*>(Pv);
    const int t    = threadIdx.x;
    const int lane = t & 63;
    const int wv   = t >> 6;
    const int n16  = lane & 15;
    const int qd   = lane >> 4;
    const int row0 = blockIdx.x * 16;
    const int col0 = wv * 32;

    half8_t a[4];
#pragma unroll
    for (int kb = 0; kb < 4; ++kb)
        a[kb] = *reinterpret_cast<const half8_t*>(
            P + (size_t)(row0 + n16) * EMB + kb * 32 + qd * 8);

    const f32x4 zc = {0.f, 0.f, 0.f, 0.f};
#pragma unroll
    for (int et = 0; et < 2; ++et) {
        const int e = col0 + et * 16 + n16;
        f32x4 acc = zc;
#pragma unroll
        for (int kb = 0; kb < 4; ++kb) {
            const float* wp = W + (size_t)e * EMB + kb * 32 + qd * 8;
            float4 w0 = *reinterpret_cast<const float4*>(wp);
            float4 w1 = *reinterpret_cast<const float4*>(wp + 4);
            half2_t h0 = pkrtz(w0.x, w0.y);
            half2_t h1 = pkrtz(w0.z, w0.w);
            half2_t h2 = pkrtz(w1.x, w1.y);
            half2_t h3 = pkrtz(w1.z, w1.w);
            half8_t bfr;
            bfr[0] = h0[0]; bfr[1] = h0[1]; bfr[2] = h1[0]; bfr[3] = h1[1];
            bfr[4] = h2[0]; bfr[5] = h2[1]; bfr[6] = h3[0]; bfr[7] = h3[1];
            acc = __builtin_amdgcn_mfma_f32_16x16x32_f16(a[kb], bfr, acc, 0, 0, 0);
        }
        const float bv = bias[e];
#pragma unroll
        for (int r = 0; r < 4; ++r)
            out[(size_t)(row0 + qd * 4 + r) * EMB + e] = acc[r] + bv;
    }
}

extern "C" void kernel_launch(void* const* d_in, const int* in_sizes, int n_in,
                              void* d_out, int out_size, void* d_ws, size_t ws_size,
                              hipStream_t stream)
{
    const float* x     = (const float*)d_in[0];
    const float* theta = (const float*)d_in[1];
    const float* W     = (const float*)d_in[2];
    const float* bias  = (const float*)d_in[3];
    float* out = (float*)d_out;

    __fp16* Pw = (__fp16*)d_ws;                              // 2 MB

    qattn_mfma<<<128 * 8, 256, 0, stream>>>(x, theta, Pw);
    proj_mfma<<<BATCH * SEQ / 16, 256, 0, stream>>>(Pw, W, bias, out);
}

// Round 15
// 89.088 us; speedup vs baseline: 1.0871x; 1.0032x over previous
//
#include <hip/hip_runtime.h>

#define NHEADS 16
#define NW 8
#define SEQ 1024
#define BATCH 8
#define EMB 128

typedef _Float16 half2_t __attribute__((ext_vector_type(2)));
typedef _Float16 half4_t __attribute__((ext_vector_type(4)));
typedef _Float16 half8_t __attribute__((ext_vector_type(8)));
typedef float    f32x4   __attribute__((ext_vector_type(4)));
typedef int      i32x2   __attribute__((ext_vector_type(2)));

__device__ __forceinline__ half2_t pkrtz(float a, float b) {
    return __builtin_bit_cast(half2_t, __builtin_amdgcn_cvt_pkrtz(a, b));
}

#if __has_builtin(__builtin_amdgcn_permlane16_swap)
#define HAVE_PLSWAP 1
#else
#define HAVE_PLSWAP 0
#endif

// qattn smem layout in halves:
//   kvh  [1024 keys][8 dims]      @ 0        (16 KB, row-major)
//   kvhT [8 dims][stride 1042]    @ 8192     (transposed; dword stride 521 == 9 mod 32)
//   ones [8] / zero [8]           @ 16528 / 16536
#define KVT       8192
#define KVT_STR   1042
#define ONES_OFF  (KVT + 8 * KVT_STR)      // 16528
#define ZERO_OFF  (ONES_OFF + 8)           // 16536
#define SMEM_H    (ZERO_OFF + 88)          // slack for last-iter prefetch overrun

// quantum_heads closed form for one (b,s,head) row (fp32 input):
// c[w] = cos(x[w] + theta[w]); z[0] = c1..c7; z[w>=1] = c0..cw
__device__ __forceinline__ void qrow(const float* __restrict__ xp,
                                     const float* __restrict__ th, float* z) {
    float4 a = *reinterpret_cast<const float4*>(xp);
    float4 b = *reinterpret_cast<const float4*>(xp + 4);
    float c0 = __cosf(a.x + th[0]);
    float c1 = __cosf(a.y + th[1]);
    float c2 = __cosf(a.z + th[2]);
    float c3 = __cosf(a.w + th[3]);
    float c4 = __cosf(b.x + th[4]);
    float c5 = __cosf(b.y + th[5]);
    float c6 = __cosf(b.z + th[6]);
    float c7 = __cosf(b.w + th[7]);
    float u = c1 * c2;
    u *= c3; u *= c4; u *= c5; u *= c6; u *= c7;
    z[0] = u;
    z[1] = c0 * c1;
    z[2] = z[1] * c2;
    z[3] = z[2] * c3;
    z[4] = z[3] * c4;
    z[5] = z[4] * c5;
    z[6] = z[5] * c6;
    z[7] = z[6] * c7;
}

// MFMA attention (R11/R14-verified layouts; 64 keys per K-iter for a wider
// scheduling window). grid = 128 bh * 8 qsplits = 1024 blocks, 256 threads.
__global__ __launch_bounds__(256, 4) void qattn_mfma(
    const float* __restrict__ x,
    const float* __restrict__ theta,
    __fp16* __restrict__ P)        // [B*S][128] f16, normalized attn@h
{
    __shared__ __align__(16) _Float16 smem[SMEM_H];
    const int t   = threadIdx.x;
    const int bid = blockIdx.x;
    const int qs  = bid & 7;                // query octant (128 q)
    const int bh  = bid >> 3;               // 0..127
    const int b   = bh >> 4, h = bh & 15;

    float th[8];
#pragma unroll
    for (int w = 0; w < 8; ++w) th[w] = theta[w];   // wave-uniform -> s_loads

    // ---- stage all 1024 keys: row-major f16 + transposed copy ----
#pragma unroll
    for (int i = 0; i < 4; ++i) {
        const int kl = t + 256 * i;
        float z[8];
        qrow(x + ((size_t)(b * SEQ + kl) * EMB + h * NW), th, z);
        half8_t hv;
#pragma unroll
        for (int d = 0; d < 8; ++d) hv[d] = (_Float16)z[d];
        *reinterpret_cast<half8_t*>(&smem[kl * 8]) = hv;
#pragma unroll
        for (int d = 0; d < 8; ++d) smem[KVT + d * KVT_STR + kl] = hv[d];
    }
    if (t < 8)              smem[ONES_OFF + t]     = (_Float16)1.0f;
    else if (t < 16)        smem[ZERO_OFF + t - 8] = (_Float16)0.0f;
    __syncthreads();

    const int lane = t & 63;
    const int wv   = t >> 6;
    const int q16  = lane & 15;
    const int qd   = lane >> 4;             // quad 0..3
    const int qbase = qs * 128 + wv * 32;

    // ---- Q fragments (B operand): B[k=dim][n=q], quads!=0 read zeros ----
    const _Float16 QSh = (_Float16)0.51012924f;   // (1/sqrt(8))*log2(e)
    half8_t qfrag[2];
#pragma unroll
    for (int qi = 0; qi < 2; ++qi) {
        const _Float16* qp = (qd == 0)
            ? &smem[(qbase + qi * 16 + q16) * 8] : &smem[ZERO_OFF];
        half8_t qv = *reinterpret_cast<const half8_t*>(qp);
#pragma unroll
        for (int j = 0; j < 8; ++j) qv[j] = qv[j] * QSh;
        qfrag[qi] = qv;
    }

    // ---- loop-invariant pointers / lane constants ----
    // K A-frags: quad 0 lanes read real rows, others a zero row.
    const _Float16* pK = (qd == 0) ? &smem[q16 * 8] : &smem[ZERO_OFF];
    const int o16  = (qd == 0) ? 128 : 0;          // 16 keys in halves
    const int kst  = (qd == 0) ? 512 : 0;          // 64 keys in halves

    // V-operand (A-op of PV MFMA) dword loads; key order kappa matches the
    // permlane-swap output (or consecutive for the bpermute fallback).
    const unsigned int* vb; int vo0, vo1, vo2, vo3; int vstep;
    if (q16 < 8) {
        vb = reinterpret_cast<const unsigned int*>(&smem[KVT + q16 * KVT_STR]);
#if HAVE_PLSWAP
        const int bo = (qd & 1) + (qd >> 1) * 4;
        vo0 = bo; vo1 = bo + 2; vo2 = bo + 8; vo3 = bo + 10;
#else
        vo0 = qd * 4; vo1 = vo0 + 1; vo2 = vo0 + 2; vo3 = vo0 + 3;
#endif
        vstep = 32;                                // 64 keys = 32 dwords
    } else if (q16 == 8) {
        vb = reinterpret_cast<const unsigned int*>(&smem[ONES_OFF]);
        vo0 = vo1 = vo2 = vo3 = 0; vstep = 0;
    } else {
        vb = reinterpret_cast<const unsigned int*>(&smem[ZERO_OFF]);
        vo0 = vo1 = vo2 = vo3 = 0; vstep = 0;
    }
    const int vg1 = (q16 < 8) ? 16 : 0;            // 2nd 32-key group offset (dwords)

#if !HAVE_PLSWAP
    const bool oddq = (qd & 1);
    const bool hiC  = (qd >= 2);
    const int  iA   = (q16 + (qd & 1) * 32 + (qd >> 1) * 16) * 4;
    const int  iB   = iA ^ 64;
#endif
    const int  lidx = (32 + q16) * 4;              // lane holding dim-8 row (l)

    f32x4 oacc[2] = {{0.f, 0.f, 0.f, 0.f}, {0.f, 0.f, 0.f, 0.f}};
    const f32x4 zc = {0.f, 0.f, 0.f, 0.f};

    half8_t kA0 = *reinterpret_cast<const half8_t*>(pK);
    half8_t kB0 = *reinterpret_cast<const half8_t*>(pK + o16);
    half8_t kA1 = *reinterpret_cast<const half8_t*>(pK + 2 * o16);
    half8_t kB1 = *reinterpret_cast<const half8_t*>(pK + 3 * o16);
    unsigned int w0 = vb[vo0],      w1 = vb[vo1],      w2 = vb[vo2],      w3 = vb[vo3];
    unsigned int w4 = vb[vg1 + vo0], w5 = vb[vg1 + vo1], w6 = vb[vg1 + vo2], w7 = vb[vg1 + vo3];

    for (int kt = 0; kt < 16; ++kt) {
        pK += kst; vb += vstep;
        // prefetch next 64 keys (pad-safe on last iter)
        half8_t nA0 = *reinterpret_cast<const half8_t*>(pK);
        half8_t nB0 = *reinterpret_cast<const half8_t*>(pK + o16);
        half8_t nA1 = *reinterpret_cast<const half8_t*>(pK + 2 * o16);
        half8_t nB1 = *reinterpret_cast<const half8_t*>(pK + 3 * o16);
        unsigned int n0 = vb[vo0],      n1 = vb[vo1],      n2 = vb[vo2],      n3 = vb[vo3];
        unsigned int n4 = vb[vg1 + vo0], n5 = vb[vg1 + vo1], n6 = vb[vg1 + vo2], n7 = vb[vg1 + vo3];

        union { unsigned int i[4]; half8_t h; } vf0, vf1;
        vf0.i[0] = w0; vf0.i[1] = w1; vf0.i[2] = w2; vf0.i[3] = w3;
        vf1.i[0] = w4; vf1.i[1] = w5; vf1.i[2] = w6; vf1.i[3] = w7;

#pragma unroll
        for (int qi = 0; qi < 2; ++qi) {
#pragma unroll
            for (int g = 0; g < 2; ++g) {
                const half8_t kA = g ? kA1 : kA0;
                const half8_t kB = g ? kB1 : kB0;
                // S^T tiles: C[row=key=qd*4+reg][col=q=lane&15]
                f32x4 c0 = __builtin_amdgcn_mfma_f32_16x16x32_f16(kA, qfrag[qi], zc, 0, 0, 0);
                f32x4 c1 = __builtin_amdgcn_mfma_f32_16x16x32_f16(kB, qfrag[qi], zc, 0, 0, 0);
                half2_t p0 = pkrtz(__builtin_amdgcn_exp2f(c0[0]), __builtin_amdgcn_exp2f(c0[1]));
                half2_t p1 = pkrtz(__builtin_amdgcn_exp2f(c0[2]), __builtin_amdgcn_exp2f(c0[3]));
                half2_t p2 = pkrtz(__builtin_amdgcn_exp2f(c1[0]), __builtin_amdgcn_exp2f(c1[1]));
                half2_t p3 = pkrtz(__builtin_amdgcn_exp2f(c1[2]), __builtin_amdgcn_exp2f(c1[3]));
                union { half2_t h; int i; } u0, u1, u2, u3;
                u0.h = p0; u1.h = p1; u2.h = p2; u3.h = p3;
                union { int i[4]; half8_t h; } bf;
#if HAVE_PLSWAP
                i32x2 s01 = __builtin_amdgcn_permlane16_swap(u0.i, u1.i, false, false);
                i32x2 s23 = __builtin_amdgcn_permlane16_swap(u2.i, u3.i, false, false);
                bf.i[0] = s01[0]; bf.i[1] = s01[1];
                bf.i[2] = s23[0]; bf.i[3] = s23[1];
#else
                const int a0 = oddq ? u2.i : u0.i;
                const int a1 = oddq ? u3.i : u1.i;
                const int a2 = oddq ? u0.i : u2.i;
                const int a3 = oddq ? u1.i : u3.i;
                const int r0 = __builtin_amdgcn_ds_bpermute(iA, a0);
                const int r1 = __builtin_amdgcn_ds_bpermute(iA, a1);
                const int r2 = __builtin_amdgcn_ds_bpermute(iB, a2);
                const int r3 = __builtin_amdgcn_ds_bpermute(iB, a3);
                bf.i[0] = hiC ? r2 : r0;
                bf.i[1] = hiC ? r3 : r1;
                bf.i[2] = hiC ? r0 : r2;
                bf.i[3] = hiC ? r1 : r3;
#endif
                // O^T += Vx^T . P^T  (ones col -> row-sum l in dim 8)
                oacc[qi] = __builtin_amdgcn_mfma_f32_16x16x32_f16(
                    g ? vf1.h : vf0.h, bf.h, oacc[qi], 0, 0, 0);
            }
        }
        kA0 = nA0; kB0 = nB0; kA1 = nA1; kB1 = nB1;
        w0 = n0; w1 = n1; w2 = n2; w3 = n3;
        w4 = n4; w5 = n5; w6 = n6; w7 = n7;
    }

    // ---- epilogue: normalize by l (row 8 = quad2 reg0), write P f16 ----
#pragma unroll
    for (int qi = 0; qi < 2; ++qi) {
        f32x4 c = oacc[qi];
        const float lsum = __int_as_float(
            __builtin_amdgcn_ds_bpermute(lidx, __float_as_int(c[0])));
        const float inv = 1.0f / lsum;
        if (qd < 2) {                       // quads 0,1 hold dims 0-7
            half2_t u0 = pkrtz(c[0] * inv, c[1] * inv);
            half2_t u1 = pkrtz(c[2] * inv, c[3] * inv);
            half4_t o4; o4[0] = u0[0]; o4[1] = u0[1]; o4[2] = u1[0]; o4[3] = u1[1];
            const int row = b * SEQ + qbase + qi * 16 + q16;
            *reinterpret_cast<half4_t*>(
                reinterpret_cast<_Float16*>(P) + (size_t)row * EMB + h * NW + qd * 4) = o4;
        }
    }
}

// MFMA projection with fused W f32->f16 conversion (R12-verified):
// out[row][e] = sum_f P[row][f]*W[e][f] + bias[e]. No LDS, no barriers.
__global__ __launch_bounds__(256) void proj_mfma(
    const __fp16* __restrict__ Pv,
    const float* __restrict__ W,
    const float* __restrict__ bias,
    float* __restrict__ out)
{
    const _Float16* P = reinterpret_cast<const _Float16*>(Pv);
    const int t    = threadIdx.x;
    const int lane = t & 63;
    const int wv   = t >> 6;
    const int n16  = lane & 15;
    const int qd   = lane >> 4;
    const int row0 = blockIdx.x * 16;
    const int col0 = wv * 32;

    half8_t a[4];
#pragma unroll
    for (int kb = 0; kb < 4; ++kb)
        a[kb] = *reinterpret_cast<const half8_t*>(
            P + (size_t)(row0 + n16) * EMB + kb * 32 + qd * 8);

    const f32x4 zc = {0.f, 0.f, 0.f, 0.f};
#pragma unroll
    for (int et = 0; et < 2; ++et) {
        const int e = col0 + et * 16 + n16;
        f32x4 acc = zc;
#pragma unroll
        for (int kb = 0; kb < 4; ++kb) {
            const float* wp = W + (size_t)e * EMB + kb * 32 + qd * 8;
            float4 w0 = *reinterpret_cast<const float4*>(wp);
            float4 w1 = *reinterpret_cast<const float4*>(wp + 4);
            half2_t h0 = pkrtz(w0.x, w0.y);
            half2_t h1 = pkrtz(w0.z, w0.w);
            half2_t h2 = pkrtz(w1.x, w1.y);
            half2_t h3 = pkrtz(w1.z, w1.w);
            half8_t bfr;
            bfr[0] = h0[0]; bfr[1] = h0[1]; bfr[2] = h1[0]; bfr[3] = h1[1];
            bfr[4] = h2[0]; bfr[5] = h2[1]; bfr[6] = h3[0]; bfr[7] = h3[1];
            acc = __builtin_amdgcn_mfma_f32_16x16x32_f16(a[kb], bfr, acc, 0, 0, 0);
        }
        const float bv = bias[e];
#pragma unroll
        for (int r = 0; r < 4; ++r)
            out[(size_t)(row0 + qd * 4 + r) * EMB + e] = acc[r] + bv;
    }
}

extern "C" void kernel_launch(void* const* d_in, const int* in_sizes, int n_in,
                              void* d_out, int out_size, void* d_ws, size_t ws_size,
                              hipStream_t stream)
{
    const float* x     = (const float*)d_in[0];
    const float* theta = (const float*)d_in[1];
    const float* W     = (const float*)d_in[2];
    const float* bias  = (const float*)d_in[3];
    float* out = (float*)d_out;

    __fp16* Pw = (__fp16*)d_ws;                              // 2 MB

    qattn_mfma<<<128 * 8, 256, 0, stream>>>(x, theta, Pw);
    proj_mfma<<<BATCH * SEQ / 16, 256, 0, stream>>>(Pw, W, bias, out);
}